// Round 1
// baseline (604.462 us; speedup 1.0000x reference)
//
#include <hip/hip_runtime.h>
#include <stdint.h>

// Problem constants (general n/e taken from in_sizes at launch)
#define IN_F 768
#define HID 256
#define OUTF 128

typedef short bf16x8 __attribute__((ext_vector_type(8)));
typedef float f32x4 __attribute__((ext_vector_type(4)));

__device__ inline short f2bf(float f) {
  union { float f; uint32_t u; } x; x.f = f;
  uint32_t r = (x.u + 0x7fffu + ((x.u >> 16) & 1u)) >> 16;  // RNE, inputs finite
  return (short)(uint16_t)r;
}
__device__ inline float bf2f(uint32_t bits) {
  union { uint32_t u; float f; } x; x.u = bits << 16; return x.f;
}

// ---------------- CSR build ----------------
__global__ void k_zero(int* p, int n) {
  int i = blockIdx.x * blockDim.x + threadIdx.x;
  if (i < n) p[i] = 0;
}

__global__ void k_hist(const int* __restrict__ dst, int* __restrict__ cnt, int e) {
  int i = blockIdx.x * blockDim.x + threadIdx.x;
  if (i < e) atomicAdd(&cnt[dst[i]], 1);
}

// single-block scan over n counts -> row_ptr, cursor; dinv = rsqrt(cnt+1) (self-loop)
__global__ void k_scan(const int* __restrict__ cnt, int* __restrict__ rowp,
                       int* __restrict__ cursor, float* __restrict__ dinv, int n) {
  __shared__ int sm[1024];
  __shared__ int carry_s;
  int tid = threadIdx.x;
  if (tid == 0) carry_s = 0;
  __syncthreads();
  for (int base = 0; base < n; base += 1024) {
    int i = base + tid;
    int v = (i < n) ? cnt[i] : 0;
    sm[tid] = v;
    __syncthreads();
    for (int off = 1; off < 1024; off <<= 1) {
      int t = (tid >= off) ? sm[tid - off] : 0;
      __syncthreads();
      sm[tid] += t;
      __syncthreads();
    }
    int incl = sm[tid];
    int carry = carry_s;
    if (i < n) {
      int start = carry + incl - v;
      rowp[i] = start;
      cursor[i] = start;
      dinv[i] = rsqrtf((float)(v + 1));
    }
    __syncthreads();
    if (tid == 1023) carry_s = carry + sm[1023];
    __syncthreads();
  }
  if (tid == 0) rowp[n] = carry_s;
}

__global__ void k_fill(const int* __restrict__ src, const int* __restrict__ dst,
                       int* __restrict__ cursor, int* __restrict__ ssrc, int e) {
  int i = blockIdx.x * blockDim.x + threadIdx.x;
  if (i < e) {
    int d = dst[i];
    int pos = atomicAdd(&cursor[d], 1);
    ssrc[pos] = src[i];
  }
}

// transpose+convert weights: W[K][N] f32 -> Wt[N][K] bf16
__global__ void k_tw(const float* __restrict__ W, short* __restrict__ Wt, int K, int N) {
  int idx = blockIdx.x * blockDim.x + threadIdx.x;
  if (idx < K * N) {
    int nn = idx / K, kk = idx - nn * K;
    Wt[idx] = f2bf(W[kk * N + nn]);
  }
}

// ---------------- MFMA GEMM: C[M,N](bf16) = A[M,K] @ Bt[N,K]^T ----------------
// 128x128 tile, BK=32, 256 threads (2x2 waves of 64x64), mfma_f32_16x16x32_bf16.
// A is f32 (converted during staging) or bf16 (short). N,K multiples of 128/32; M ragged.
template <typename TA>
__global__ __launch_bounds__(256) void k_gemm(const TA* __restrict__ A,
                                              const short* __restrict__ Bt,
                                              short* __restrict__ C,
                                              int M, int N, int K) {
  __shared__ short As[128 * 32];
  __shared__ short Bs[128 * 32];
  const int tid = threadIdx.x;
  const int tile_m = blockIdx.x * 128;
  const int tile_n = blockIdx.y * 128;
  const int wave = tid >> 6;
  const int lane = tid & 63;
  const int wm = (wave & 1) * 64;
  const int wn = (wave >> 1) * 64;
  const int lrow = lane & 15;
  const int quad = lane >> 4;

  f32x4 zero = {0.f, 0.f, 0.f, 0.f};
  f32x4 acc[4][4];
#pragma unroll
  for (int i = 0; i < 4; i++)
#pragma unroll
    for (int j = 0; j < 4; j++) acc[i][j] = zero;

  for (int k0 = 0; k0 < K; k0 += 32) {
    // stage A: 512 chunks of 8 elems; thread handles chunks tid, tid+256
#pragma unroll
    for (int c0 = 0; c0 < 2; ++c0) {
      int c = tid + c0 * 256;
      int row = c >> 2;
      int col = (c & 3) * 8;
      int gr = tile_m + row;
      if (gr >= M) gr = M - 1;  // clamp; padded rows discarded at store
      if constexpr (sizeof(TA) == 4) {
        const float* s = (const float*)A + (size_t)gr * K + k0 + col;
        float4 v0 = *(const float4*)s;
        float4 v1 = *(const float4*)(s + 4);
        bf16x8 pk;
        pk[0] = f2bf(v0.x); pk[1] = f2bf(v0.y); pk[2] = f2bf(v0.z); pk[3] = f2bf(v0.w);
        pk[4] = f2bf(v1.x); pk[5] = f2bf(v1.y); pk[6] = f2bf(v1.z); pk[7] = f2bf(v1.w);
        *(bf16x8*)&As[c * 8] = pk;
      } else {
        *(bf16x8*)&As[c * 8] =
            *(const bf16x8*)((const short*)A + (size_t)gr * K + k0 + col);
      }
    }
    // stage B (bf16, N multiple of 128 so no clamp)
#pragma unroll
    for (int c0 = 0; c0 < 2; ++c0) {
      int c = tid + c0 * 256;
      int row = c >> 2;
      int col = (c & 3) * 8;
      *(bf16x8*)&Bs[c * 8] =
          *(const bf16x8*)(Bt + (size_t)(tile_n + row) * K + k0 + col);
    }
    __syncthreads();

    bf16x8 af[4], bfr[4];
#pragma unroll
    for (int i = 0; i < 4; i++)
      af[i] = *(const bf16x8*)&As[(wm + i * 16 + lrow) * 32 + quad * 8];
#pragma unroll
    for (int j = 0; j < 4; j++)
      bfr[j] = *(const bf16x8*)&Bs[(wn + j * 16 + lrow) * 32 + quad * 8];
#pragma unroll
    for (int i = 0; i < 4; i++)
#pragma unroll
      for (int j = 0; j < 4; j++)
        acc[i][j] = __builtin_amdgcn_mfma_f32_16x16x32_bf16(af[i], bfr[j],
                                                            acc[i][j], 0, 0, 0);
    __syncthreads();
  }

  // store: D row=(lane>>4)*4+r, col=lane&15 within each 16x16 fragment
#pragma unroll
  for (int i = 0; i < 4; i++) {
#pragma unroll
    for (int r = 0; r < 4; r++) {
      int grow = tile_m + wm + i * 16 + quad * 4 + r;
      if (grow < M) {
#pragma unroll
        for (int j = 0; j < 4; j++) {
          int gcol = tile_n + wn + j * 16 + lrow;
          C[(size_t)grow * N + gcol] = f2bf(acc[i][j][r]);
        }
      }
    }
  }
}

// ---------------- CSR aggregation ----------------
// out[i,:] = bias + dinv[i]*( dinv[i]*H[i,:] + sum_e dinv[src]*H[src,:] ), opt ReLU
// F feats, F/2 threads/block (2 bf16 per thread via uint load).
template <int F, bool RELU, typename OT>
__global__ void k_agg(const short* __restrict__ Hin, const int* __restrict__ rowp,
                      const int* __restrict__ ssrc, const float* __restrict__ dinv,
                      const float* __restrict__ bias, OT* __restrict__ out) {
  int i = blockIdx.x;
  int t = threadIdx.x;  // 0..F/2-1
  float di = dinv[i];
  uint32_t u = *(const uint32_t*)&Hin[(size_t)i * F + 2 * t];
  float acc0 = di * bf2f(u & 0xffffu);
  float acc1 = di * bf2f(u >> 16);
  int e0 = rowp[i], e1 = rowp[i + 1];
  for (int p = e0; p < e1; ++p) {
    int s = ssrc[p];
    float ds = dinv[s];
    uint32_t v = *(const uint32_t*)&Hin[(size_t)s * F + 2 * t];
    acc0 += ds * bf2f(v & 0xffffu);
    acc1 += ds * bf2f(v >> 16);
  }
  float o0 = di * acc0 + bias[2 * t];
  float o1 = di * acc1 + bias[2 * t + 1];
  if (RELU) { o0 = fmaxf(o0, 0.f); o1 = fmaxf(o1, 0.f); }
  if constexpr (sizeof(OT) == 2) {
    out[(size_t)i * F + 2 * t] = f2bf(o0);
    out[(size_t)i * F + 2 * t + 1] = f2bf(o1);
  } else {
    out[(size_t)i * F + 2 * t] = o0;
    out[(size_t)i * F + 2 * t + 1] = o1;
  }
}

// ---------------- launch ----------------
extern "C" void kernel_launch(void* const* d_in, const int* in_sizes, int n_in,
                              void* d_out, int out_size, void* d_ws, size_t ws_size,
                              hipStream_t stream) {
  const float* x = (const float*)d_in[0];
  const int* ei = (const int*)d_in[1];
  const float* W1 = (const float*)d_in[2];
  const float* b1 = (const float*)d_in[3];
  const float* W2 = (const float*)d_in[4];
  const float* b2 = (const float*)d_in[5];
  float* out = (float*)d_out;

  const int n = in_sizes[0] / IN_F;   // 50000
  const int e = in_sizes[1] / 2;      // 800000
  const int* e_src = ei;
  const int* e_dst = ei + e;

  // workspace carve-up (256B aligned)
  uint8_t* ws = (uint8_t*)d_ws;
  size_t off = 0;
  auto carve = [&](size_t bytes) {
    uint8_t* p = ws + off;
    off = (off + bytes + 255) & ~(size_t)255;
    return p;
  };
  short* h1 = (short*)carve((size_t)n * HID * 2);      // GEMM1 out, bf16
  short* h2 = (short*)carve((size_t)n * HID * 2);      // agg1 out (ReLU), bf16
  short* t2 = (short*)carve((size_t)n * OUTF * 2);     // GEMM2 out, bf16
  short* w1t = (short*)carve((size_t)HID * IN_F * 2);  // W1^T bf16 [256][768]
  short* w2t = (short*)carve((size_t)OUTF * HID * 2);  // W2^T bf16 [128][256]
  int* cnt = (int*)carve((size_t)n * 4);
  int* rowp = (int*)carve((size_t)(n + 1) * 4);
  int* cursor = (int*)carve((size_t)n * 4);
  float* dinv = (float*)carve((size_t)n * 4);
  int* ssrc = (int*)carve((size_t)e * 4);
  (void)ws_size; (void)n_in; (void)out_size;

  // CSR build
  k_zero<<<(n + 255) / 256, 256, 0, stream>>>(cnt, n);
  k_hist<<<(e + 255) / 256, 256, 0, stream>>>(e_dst, cnt, e);
  k_scan<<<1, 1024, 0, stream>>>(cnt, rowp, cursor, dinv, n);
  k_fill<<<(e + 255) / 256, 256, 0, stream>>>(e_src, e_dst, cursor, ssrc, e);

  // weight transpose+convert
  k_tw<<<(IN_F * HID + 255) / 256, 256, 0, stream>>>(W1, w1t, IN_F, HID);
  k_tw<<<(HID * OUTF + 255) / 256, 256, 0, stream>>>(W2, w2t, HID, OUTF);

  // layer 1: h1 = x @ W1 ; h2 = relu(agg(h1) + b1)
  {
    dim3 grid((n + 127) / 128, HID / 128);
    k_gemm<float><<<grid, 256, 0, stream>>>(x, w1t, h1, n, HID, IN_F);
  }
  k_agg<HID, true, short><<<n, HID / 2, 0, stream>>>(h1, rowp, ssrc, dinv, b1, h2);

  // layer 2: t2 = h2 @ W2 ; out = agg(t2) + b2
  {
    dim3 grid((n + 127) / 128, OUTF / 128);
    k_gemm<short><<<grid, 256, 0, stream>>>(h2, w2t, t2, n, OUTF, HID);
  }
  k_agg<OUTF, false, float><<<n, OUTF / 2, 0, stream>>>(t2, rowp, ssrc, dinv, b2, out);
}

// Round 2
// 489.274 us; speedup vs baseline: 1.2354x; 1.2354x over previous
//
#include <hip/hip_runtime.h>
#include <stdint.h>

#define IN_F 768
#define HID 256
#define OUTF 128

typedef short bf16x8 __attribute__((ext_vector_type(8)));
typedef float f32x4 __attribute__((ext_vector_type(4)));

__device__ inline short f2bf(float f) {
  union { float f; uint32_t u; } x; x.f = f;
  uint32_t r = (x.u + 0x7fffu + ((x.u >> 16) & 1u)) >> 16;  // RNE, finite inputs
  return (short)(uint16_t)r;
}
__device__ inline float bf2f(uint32_t bits) {
  union { uint32_t u; float f; } x; x.u = bits << 16; return x.f;
}

// ---------------- CSR build ----------------
__global__ void k_zero(int* p, int n) {
  int i = blockIdx.x * blockDim.x + threadIdx.x;
  if (i < n) p[i] = 0;
}

__global__ void k_hist(const int* __restrict__ dst, int* __restrict__ cnt, int e) {
  int i = blockIdx.x * blockDim.x + threadIdx.x;
  if (i < e) atomicAdd(&cnt[dst[i]], 1);
}

#define SCAN_B 1024
// per-block sum of cnt
__global__ void k_bsum(const int* __restrict__ cnt, int* __restrict__ bsum, int n) {
  __shared__ int sm[SCAN_B];
  int t = threadIdx.x;
  int i = blockIdx.x * SCAN_B + t;
  sm[t] = (i < n) ? cnt[i] : 0;
  __syncthreads();
  for (int off = SCAN_B / 2; off > 0; off >>= 1) {
    if (t < off) sm[t] += sm[t + off];
    __syncthreads();
  }
  if (t == 0) bsum[blockIdx.x] = sm[0];
}

// exclusive scan of nb block sums (nb <= 64 fast path; serial fallback)
__global__ void k_bscan(const int* __restrict__ bsum, int* __restrict__ boff, int nb) {
  int l = threadIdx.x;
  if (nb <= 64) {
    int v = (l < nb) ? bsum[l] : 0;
    int incl = v;
#pragma unroll
    for (int off = 1; off < 64; off <<= 1) {
      int t = __shfl_up(incl, off);
      if (l >= off) incl += t;
    }
    if (l < nb) boff[l] = incl - v;
  } else if (l == 0) {
    int run = 0;
    for (int b = 0; b < nb; ++b) { boff[b] = run; run += bsum[b]; }
  }
}

// local scan + block offset -> rowp, cursor, dinv
__global__ void k_scan2(const int* __restrict__ cnt, const int* __restrict__ boff,
                        int* __restrict__ rowp, int* __restrict__ cursor,
                        float* __restrict__ dinv, int n) {
  __shared__ int sm[SCAN_B];
  int t = threadIdx.x;
  int i = blockIdx.x * SCAN_B + t;
  int v = (i < n) ? cnt[i] : 0;
  sm[t] = v;
  __syncthreads();
  for (int off = 1; off < SCAN_B; off <<= 1) {
    int tv = (t >= off) ? sm[t - off] : 0;
    __syncthreads();
    sm[t] += tv;
    __syncthreads();
  }
  int incl = sm[t] + boff[blockIdx.x];
  if (i < n) {
    int start = incl - v;
    rowp[i] = start;
    cursor[i] = start;
    dinv[i] = rsqrtf((float)(v + 1));
    if (i == n - 1) rowp[n] = incl;
  }
}

__global__ void k_fill(const int* __restrict__ src, const int* __restrict__ dst,
                       int* __restrict__ cursor, int* __restrict__ ssrc, int e) {
  int i = blockIdx.x * blockDim.x + threadIdx.x;
  if (i < e) {
    int d = dst[i];
    int pos = atomicAdd(&cursor[d], 1);
    ssrc[pos] = src[i];
  }
}

// transpose+convert weights: W[K][N] f32 -> Wt[N][K] bf16
__global__ void k_tw(const float* __restrict__ W, short* __restrict__ Wt, int K, int N) {
  int idx = blockIdx.x * blockDim.x + threadIdx.x;
  if (idx < K * N) {
    int nn = idx / K, kk = idx - nn * K;
    Wt[idx] = f2bf(W[kk * N + nn]);
  }
}

// convert x f32 -> bf16, 8 elems/thread
__global__ void k_cvt(const float* __restrict__ x, short* __restrict__ xb, int total8) {
  int i = blockIdx.x * blockDim.x + threadIdx.x;
  if (i < total8) {
    const float4* s = (const float4*)x + (size_t)i * 2;
    float4 v0 = s[0], v1 = s[1];
    bf16x8 pk;
    pk[0] = f2bf(v0.x); pk[1] = f2bf(v0.y); pk[2] = f2bf(v0.z); pk[3] = f2bf(v0.w);
    pk[4] = f2bf(v1.x); pk[5] = f2bf(v1.y); pk[6] = f2bf(v1.z); pk[7] = f2bf(v1.w);
    *(bf16x8*)(xb + (size_t)i * 8) = pk;
  }
}

// ---------------- async MFMA GEMM (m97 structure) ----------------
// C[M,N](bf16) = A[M,K](bf16) @ Bt[N,K]^T. 128x128 tile, BK=32, 256 thr.
__device__ inline void glds16(const short* g, short* l) {
  __builtin_amdgcn_global_load_lds((const __attribute__((address_space(1))) void*)g,
                                   (__attribute__((address_space(3))) void*)l, 16, 0, 0);
}

__global__ __launch_bounds__(256) void k_gemm_a(const short* __restrict__ A,
                                                const short* __restrict__ Bt,
                                                short* __restrict__ C,
                                                int M, int N, int K) {
  __shared__ __align__(16) short As[128 * 32];
  __shared__ __align__(16) short Bs[128 * 32];
  const int tid = threadIdx.x;
  const int tile_m = blockIdx.x * 128;
  const int tile_n = blockIdx.y * 128;
  const int wave = tid >> 6;
  const int lane = tid & 63;
  const int wm = (wave & 1) * 64;
  const int wn = (wave >> 1) * 64;
  const int lrow = lane & 15;
  const int quad = lane >> 4;

  const int c = tid, c2 = tid + 256;
  const int rowA = c >> 2, colA = (c & 3) * 8;
  const int rowA2 = c2 >> 2, colA2 = (c2 & 3) * 8;
  int grA = tile_m + rowA;  if (grA >= M) grA = M - 1;
  int grA2 = tile_m + rowA2; if (grA2 >= M) grA2 = M - 1;
  const short* pA = A + (size_t)grA * K + colA;
  const short* pA2 = A + (size_t)grA2 * K + colA2;
  const short* pB = Bt + (size_t)(tile_n + rowA) * K + colA;
  const short* pB2 = Bt + (size_t)(tile_n + rowA2) * K + colA2;

  f32x4 zero = {0.f, 0.f, 0.f, 0.f};
  f32x4 acc[4][4];
#pragma unroll
  for (int i = 0; i < 4; i++)
#pragma unroll
    for (int j = 0; j < 4; j++) acc[i][j] = zero;

  for (int k0 = 0; k0 < K; k0 += 32) {
    glds16(pA + k0, &As[c * 8]);
    glds16(pA2 + k0, &As[c2 * 8]);
    glds16(pB + k0, &Bs[c * 8]);
    glds16(pB2 + k0, &Bs[c2 * 8]);
    __builtin_amdgcn_s_waitcnt(0xcf70);  // vmcnt(0)
    __syncthreads();

    bf16x8 af[4], bfr[4];
#pragma unroll
    for (int i = 0; i < 4; i++)
      af[i] = *(const bf16x8*)&As[(wm + i * 16 + lrow) * 32 + quad * 8];
#pragma unroll
    for (int j = 0; j < 4; j++)
      bfr[j] = *(const bf16x8*)&Bs[(wn + j * 16 + lrow) * 32 + quad * 8];
#pragma unroll
    for (int i = 0; i < 4; i++)
#pragma unroll
      for (int j = 0; j < 4; j++)
        acc[i][j] = __builtin_amdgcn_mfma_f32_16x16x32_bf16(af[i], bfr[j],
                                                            acc[i][j], 0, 0, 0);
    __syncthreads();
  }

#pragma unroll
  for (int i = 0; i < 4; i++) {
#pragma unroll
    for (int r = 0; r < 4; r++) {
      int grow = tile_m + wm + i * 16 + quad * 4 + r;
      if (grow < M) {
#pragma unroll
        for (int j = 0; j < 4; j++) {
          int gcol = tile_n + wn + j * 16 + lrow;
          C[(size_t)grow * N + gcol] = f2bf(acc[i][j][r]);
        }
      }
    }
  }
}

// ---------------- fallback GEMM (manual staging, f32 A) ----------------
template <typename TA>
__global__ __launch_bounds__(256) void k_gemm(const TA* __restrict__ A,
                                              const short* __restrict__ Bt,
                                              short* __restrict__ C,
                                              int M, int N, int K) {
  __shared__ short As[128 * 32];
  __shared__ short Bs[128 * 32];
  const int tid = threadIdx.x;
  const int tile_m = blockIdx.x * 128;
  const int tile_n = blockIdx.y * 128;
  const int wave = tid >> 6;
  const int lane = tid & 63;
  const int wm = (wave & 1) * 64;
  const int wn = (wave >> 1) * 64;
  const int lrow = lane & 15;
  const int quad = lane >> 4;

  f32x4 zero = {0.f, 0.f, 0.f, 0.f};
  f32x4 acc[4][4];
#pragma unroll
  for (int i = 0; i < 4; i++)
#pragma unroll
    for (int j = 0; j < 4; j++) acc[i][j] = zero;

  for (int k0 = 0; k0 < K; k0 += 32) {
#pragma unroll
    for (int c0 = 0; c0 < 2; ++c0) {
      int c = tid + c0 * 256;
      int row = c >> 2;
      int col = (c & 3) * 8;
      int gr = tile_m + row;
      if (gr >= M) gr = M - 1;
      if constexpr (sizeof(TA) == 4) {
        const float* s = (const float*)A + (size_t)gr * K + k0 + col;
        float4 v0 = *(const float4*)s;
        float4 v1 = *(const float4*)(s + 4);
        bf16x8 pk;
        pk[0] = f2bf(v0.x); pk[1] = f2bf(v0.y); pk[2] = f2bf(v0.z); pk[3] = f2bf(v0.w);
        pk[4] = f2bf(v1.x); pk[5] = f2bf(v1.y); pk[6] = f2bf(v1.z); pk[7] = f2bf(v1.w);
        *(bf16x8*)&As[c * 8] = pk;
      } else {
        *(bf16x8*)&As[c * 8] =
            *(const bf16x8*)((const short*)A + (size_t)gr * K + k0 + col);
      }
      *(bf16x8*)&Bs[c * 8] =
          *(const bf16x8*)(Bt + (size_t)(tile_n + row) * K + k0 + col);
    }
    __syncthreads();

    bf16x8 af[4], bfr[4];
#pragma unroll
    for (int i = 0; i < 4; i++)
      af[i] = *(const bf16x8*)&As[(wm + i * 16 + lrow) * 32 + quad * 8];
#pragma unroll
    for (int j = 0; j < 4; j++)
      bfr[j] = *(const bf16x8*)&Bs[(wn + j * 16 + lrow) * 32 + quad * 8];
#pragma unroll
    for (int i = 0; i < 4; i++)
#pragma unroll
      for (int j = 0; j < 4; j++)
        acc[i][j] = __builtin_amdgcn_mfma_f32_16x16x32_bf16(af[i], bfr[j],
                                                            acc[i][j], 0, 0, 0);
    __syncthreads();
  }

#pragma unroll
  for (int i = 0; i < 4; i++) {
#pragma unroll
    for (int r = 0; r < 4; r++) {
      int grow = tile_m + wm + i * 16 + quad * 4 + r;
      if (grow < M) {
#pragma unroll
        for (int j = 0; j < 4; j++) {
          int gcol = tile_n + wn + j * 16 + lrow;
          C[(size_t)grow * N + gcol] = f2bf(acc[i][j][r]);
        }
      }
    }
  }
}

// ---------------- CSR aggregation: wave per node, unroll-4 edge loop ------
// out[i,:] = bias + di*( di*H[i,:] + sum_e dinv[src]*H[src,:] ), opt ReLU
template <int F, bool RELU, typename OT>
__global__ __launch_bounds__(256) void k_agg2(const short* __restrict__ H,
                                              const int* __restrict__ rowp,
                                              const int* __restrict__ ssrc,
                                              const float* __restrict__ dinv,
                                              const float* __restrict__ bias,
                                              OT* __restrict__ out, int n) {
  constexpr int EPL = F / 64;  // bf16 elems per lane: 4 (F=256) or 2 (F=128)
  const int lane = threadIdx.x & 63;
  const int i = blockIdx.x * 4 + (threadIdx.x >> 6);
  if (i >= n) return;
  const int fo = lane * EPL;
  const float di = dinv[i];
  float acc[EPL];
  {
    const short* r = H + (size_t)i * F + fo;
    if constexpr (EPL == 4) {
      uint2 u = *(const uint2*)r;
      acc[0] = di * bf2f(u.x & 0xffffu); acc[1] = di * bf2f(u.x >> 16);
      acc[2] = di * bf2f(u.y & 0xffffu); acc[3] = di * bf2f(u.y >> 16);
    } else {
      uint32_t u = *(const uint32_t*)r;
      acc[0] = di * bf2f(u & 0xffffu); acc[1] = di * bf2f(u >> 16);
    }
  }
  int p = rowp[i];
  const int e1 = rowp[i + 1];
  for (; p + 4 <= e1; p += 4) {
    int s0 = __builtin_amdgcn_readfirstlane(ssrc[p]);
    int s1 = __builtin_amdgcn_readfirstlane(ssrc[p + 1]);
    int s2 = __builtin_amdgcn_readfirstlane(ssrc[p + 2]);
    int s3 = __builtin_amdgcn_readfirstlane(ssrc[p + 3]);
    float d0 = dinv[s0], d1 = dinv[s1], d2 = dinv[s2], d3 = dinv[s3];
    if constexpr (EPL == 4) {
      uint2 u0 = *(const uint2*)(H + (size_t)s0 * F + fo);
      uint2 u1 = *(const uint2*)(H + (size_t)s1 * F + fo);
      uint2 u2 = *(const uint2*)(H + (size_t)s2 * F + fo);
      uint2 u3 = *(const uint2*)(H + (size_t)s3 * F + fo);
      acc[0] += d0 * bf2f(u0.x & 0xffffu); acc[1] += d0 * bf2f(u0.x >> 16);
      acc[2] += d0 * bf2f(u0.y & 0xffffu); acc[3] += d0 * bf2f(u0.y >> 16);
      acc[0] += d1 * bf2f(u1.x & 0xffffu); acc[1] += d1 * bf2f(u1.x >> 16);
      acc[2] += d1 * bf2f(u1.y & 0xffffu); acc[3] += d1 * bf2f(u1.y >> 16);
      acc[0] += d2 * bf2f(u2.x & 0xffffu); acc[1] += d2 * bf2f(u2.x >> 16);
      acc[2] += d2 * bf2f(u2.y & 0xffffu); acc[3] += d2 * bf2f(u2.y >> 16);
      acc[0] += d3 * bf2f(u3.x & 0xffffu); acc[1] += d3 * bf2f(u3.x >> 16);
      acc[2] += d3 * bf2f(u3.y & 0xffffu); acc[3] += d3 * bf2f(u3.y >> 16);
    } else {
      uint32_t u0 = *(const uint32_t*)(H + (size_t)s0 * F + fo);
      uint32_t u1 = *(const uint32_t*)(H + (size_t)s1 * F + fo);
      uint32_t u2 = *(const uint32_t*)(H + (size_t)s2 * F + fo);
      uint32_t u3 = *(const uint32_t*)(H + (size_t)s3 * F + fo);
      acc[0] += d0 * bf2f(u0 & 0xffffu); acc[1] += d0 * bf2f(u0 >> 16);
      acc[0] += d1 * bf2f(u1 & 0xffffu); acc[1] += d1 * bf2f(u1 >> 16);
      acc[0] += d2 * bf2f(u2 & 0xffffu); acc[1] += d2 * bf2f(u2 >> 16);
      acc[0] += d3 * bf2f(u3 & 0xffffu); acc[1] += d3 * bf2f(u3 >> 16);
    }
  }
  for (; p < e1; ++p) {
    int s = __builtin_amdgcn_readfirstlane(ssrc[p]);
    float ds = dinv[s];
    if constexpr (EPL == 4) {
      uint2 u = *(const uint2*)(H + (size_t)s * F + fo);
      acc[0] += ds * bf2f(u.x & 0xffffu); acc[1] += ds * bf2f(u.x >> 16);
      acc[2] += ds * bf2f(u.y & 0xffffu); acc[3] += ds * bf2f(u.y >> 16);
    } else {
      uint32_t u = *(const uint32_t*)(H + (size_t)s * F + fo);
      acc[0] += ds * bf2f(u & 0xffffu); acc[1] += ds * bf2f(u >> 16);
    }
  }

  float o[EPL];
#pragma unroll
  for (int e2 = 0; e2 < EPL; ++e2) {
    o[e2] = di * acc[e2] + bias[fo + e2];
    if (RELU) o[e2] = fmaxf(o[e2], 0.f);
  }
  if constexpr (sizeof(OT) == 2) {
    if constexpr (EPL == 4) {
      uint2 pk;
      pk.x = (uint32_t)(uint16_t)f2bf(o[0]) | ((uint32_t)(uint16_t)f2bf(o[1]) << 16);
      pk.y = (uint32_t)(uint16_t)f2bf(o[2]) | ((uint32_t)(uint16_t)f2bf(o[3]) << 16);
      *(uint2*)((short*)out + (size_t)i * F + fo) = pk;
    } else {
      uint32_t pk = (uint32_t)(uint16_t)f2bf(o[0]) | ((uint32_t)(uint16_t)f2bf(o[1]) << 16);
      *(uint32_t*)((short*)out + (size_t)i * F + fo) = pk;
    }
  } else {
    if constexpr (EPL == 4) {
      *(float4*)((float*)out + (size_t)i * F + fo) = make_float4(o[0], o[1], o[2], o[3]);
    } else {
      *(float2*)((float*)out + (size_t)i * F + fo) = make_float2(o[0], o[1]);
    }
  }
}

// ---------------- launch ----------------
extern "C" void kernel_launch(void* const* d_in, const int* in_sizes, int n_in,
                              void* d_out, int out_size, void* d_ws, size_t ws_size,
                              hipStream_t stream) {
  const float* x = (const float*)d_in[0];
  const int* ei = (const int*)d_in[1];
  const float* W1 = (const float*)d_in[2];
  const float* b1 = (const float*)d_in[3];
  const float* W2 = (const float*)d_in[4];
  const float* b2 = (const float*)d_in[5];
  float* out = (float*)d_out;

  const int n = in_sizes[0] / IN_F;   // 50000
  const int e = in_sizes[1] / 2;      // 800000
  const int* e_src = ei;
  const int* e_dst = ei + e;
  const int nb = (n + SCAN_B - 1) / SCAN_B;

  uint8_t* ws = (uint8_t*)d_ws;
  size_t off = 0;
  auto carve = [&](size_t bytes) {
    uint8_t* p = ws + off;
    off = (off + bytes + 255) & ~(size_t)255;
    return p;
  };
  short* h1 = (short*)carve((size_t)n * HID * 2);
  short* h2 = (short*)carve((size_t)n * HID * 2);
  short* t2 = (short*)carve((size_t)n * OUTF * 2);
  short* w1t = (short*)carve((size_t)HID * IN_F * 2);
  short* w2t = (short*)carve((size_t)OUTF * HID * 2);
  int* cnt = (int*)carve((size_t)n * 4);
  int* rowp = (int*)carve((size_t)(n + 1) * 4);
  int* cursor = (int*)carve((size_t)n * 4);
  float* dinv = (float*)carve((size_t)n * 4);
  int* ssrc = (int*)carve((size_t)e * 4);
  int* bsum = (int*)carve((size_t)nb * 4);
  int* boff = (int*)carve((size_t)nb * 4);
  short* xb = (short*)carve((size_t)n * IN_F * 2);  // carved last: fallback if ws too small
  const bool have_xb = (off <= ws_size);
  (void)n_in; (void)out_size;

  // CSR build
  k_zero<<<(n + 255) / 256, 256, 0, stream>>>(cnt, n);
  k_hist<<<(e + 255) / 256, 256, 0, stream>>>(e_dst, cnt, e);
  k_bsum<<<nb, SCAN_B, 0, stream>>>(cnt, bsum, n);
  k_bscan<<<1, 64, 0, stream>>>(bsum, boff, nb);
  k_scan2<<<nb, SCAN_B, 0, stream>>>(cnt, boff, rowp, cursor, dinv, n);
  k_fill<<<(e + 255) / 256, 256, 0, stream>>>(e_src, e_dst, cursor, ssrc, e);

  // weights
  k_tw<<<(IN_F * HID + 255) / 256, 256, 0, stream>>>(W1, w1t, IN_F, HID);
  k_tw<<<(HID * OUTF + 255) / 256, 256, 0, stream>>>(W2, w2t, HID, OUTF);

  // layer 1
  if (have_xb) {
    k_cvt<<<(n * IN_F / 8 + 255) / 256, 256, 0, stream>>>(x, xb, n * IN_F / 8);
    dim3 grid((n + 127) / 128, HID / 128);
    k_gemm_a<<<grid, 256, 0, stream>>>(xb, w1t, h1, n, HID, IN_F);
  } else {
    dim3 grid((n + 127) / 128, HID / 128);
    k_gemm<float><<<grid, 256, 0, stream>>>(x, w1t, h1, n, HID, IN_F);
  }
  k_agg2<HID, true, short><<<(n + 3) / 4, 256, 0, stream>>>(h1, rowp, ssrc, dinv, b1, h2, n);

  // layer 2
  {
    dim3 grid((n + 127) / 128, OUTF / 128);
    k_gemm_a<<<grid, 256, 0, stream>>>(h2, w2t, t2, n, OUTF, HID);
  }
  k_agg2<OUTF, false, float><<<(n + 3) / 4, 256, 0, stream>>>(t2, rowp, ssrc, dinv, b2, out, n);
}

// Round 3
// 455.598 us; speedup vs baseline: 1.3267x; 1.0739x over previous
//
#include <hip/hip_runtime.h>
#include <stdint.h>

#define IN_F 768
#define HID 256
#define OUTF 128

typedef short bf16x8 __attribute__((ext_vector_type(8)));
typedef float f32x4 __attribute__((ext_vector_type(4)));

__device__ inline short f2bf(float f) {
  union { float f; uint32_t u; } x; x.f = f;
  uint32_t r = (x.u + 0x7fffu + ((x.u >> 16) & 1u)) >> 16;  // RNE, finite inputs
  return (short)(uint16_t)r;
}
__device__ inline float bf2f(uint32_t bits) {
  union { uint32_t u; float f; } x; x.u = bits << 16; return x.f;
}

// ---------------- CSR build ----------------
__global__ void k_zero(int* p, int n) {
  int i = blockIdx.x * blockDim.x + threadIdx.x;
  if (i < n) p[i] = 0;
}

__global__ void k_hist(const int* __restrict__ dst, int* __restrict__ cnt, int e) {
  int i = blockIdx.x * blockDim.x + threadIdx.x;
  if (i < e) atomicAdd(&cnt[dst[i]], 1);
}

#define SCAN_B 1024
__global__ void k_bsum(const int* __restrict__ cnt, int* __restrict__ bsum, int n) {
  __shared__ int sm[SCAN_B];
  int t = threadIdx.x;
  int i = blockIdx.x * SCAN_B + t;
  sm[t] = (i < n) ? cnt[i] : 0;
  __syncthreads();
  for (int off = SCAN_B / 2; off > 0; off >>= 1) {
    if (t < off) sm[t] += sm[t + off];
    __syncthreads();
  }
  if (t == 0) bsum[blockIdx.x] = sm[0];
}

__global__ void k_bscan(const int* __restrict__ bsum, int* __restrict__ boff, int nb) {
  int l = threadIdx.x;
  if (nb <= 64) {
    int v = (l < nb) ? bsum[l] : 0;
    int incl = v;
#pragma unroll
    for (int off = 1; off < 64; off <<= 1) {
      int t = __shfl_up(incl, off);
      if (l >= off) incl += t;
    }
    if (l < nb) boff[l] = incl - v;
  } else if (l == 0) {
    int run = 0;
    for (int b = 0; b < nb; ++b) { boff[b] = run; run += bsum[b]; }
  }
}

__global__ void k_scan2(const int* __restrict__ cnt, const int* __restrict__ boff,
                        int* __restrict__ rowp, int* __restrict__ cursor,
                        float* __restrict__ dinv, int n) {
  __shared__ int sm[SCAN_B];
  int t = threadIdx.x;
  int i = blockIdx.x * SCAN_B + t;
  int v = (i < n) ? cnt[i] : 0;
  sm[t] = v;
  __syncthreads();
  for (int off = 1; off < SCAN_B; off <<= 1) {
    int tv = (t >= off) ? sm[t - off] : 0;
    __syncthreads();
    sm[t] += tv;
    __syncthreads();
  }
  int incl = sm[t] + boff[blockIdx.x];
  if (i < n) {
    int start = incl - v;
    rowp[i] = start;
    cursor[i] = start;
    dinv[i] = rsqrtf((float)(v + 1));
    if (i == n - 1) rowp[n] = incl;
  }
}

__global__ void k_fill(const int* __restrict__ src, const int* __restrict__ dst,
                       int* __restrict__ cursor, int* __restrict__ ssrc, int e) {
  int i = blockIdx.x * blockDim.x + threadIdx.x;
  if (i < e) {
    int d = dst[i];
    int pos = atomicAdd(&cursor[d], 1);
    ssrc[pos] = src[i];
  }
}

// transpose+convert weights: W[K][N] f32 -> Wt[N][K] bf16
__global__ void k_tw(const float* __restrict__ W, short* __restrict__ Wt, int K, int N) {
  int idx = blockIdx.x * blockDim.x + threadIdx.x;
  if (idx < K * N) {
    int nn = idx / K, kk = idx - nn * K;
    Wt[idx] = f2bf(W[kk * N + nn]);
  }
}

// ---------------- GEMM1: C[M,256](bf16) = A[M,K](f32) @ Bt[256,K]^T -------
// 128x256 tile (full HID), BK=32, 256 thr, register-prefetch pipeline,
// f32->bf16 conversion fused into LDS staging. A read exactly once from HBM.
__global__ __launch_bounds__(256, 2) void k_gemm1(const float* __restrict__ A,
                                                  const short* __restrict__ Bt,
                                                  short* __restrict__ C,
                                                  int M, int K) {
  __shared__ __align__(16) short As[128 * 32];
  __shared__ __align__(16) short Bs[256 * 32];
  const int tid = threadIdx.x;
  const int tile_m = blockIdx.x * 128;
  const int wave = tid >> 6;
  const int lane = tid & 63;
  const int wm = (wave & 1) * 64;
  const int wn = (wave >> 1) * 128;
  const int lrow = lane & 15;
  const int quad = lane >> 4;

  // A staging: chunks c = tid, tid+256 (8 f32 each); row=c>>2, col=(c&3)*8
  const int rA0 = tid >> 2;
  const int colA = (tid & 3) * 8;
  const int rA1 = rA0 + 64;
  int gr0 = tile_m + rA0; if (gr0 >= M) gr0 = M - 1;
  int gr1 = tile_m + rA1; if (gr1 >= M) gr1 = M - 1;
  const float* pA0 = A + (size_t)gr0 * K + colA;
  const float* pA1 = A + (size_t)gr1 * K + colA;
  // B staging: 4 chunks c = tid + q*256; row = (tid>>2) + q*64
  const short* pB = Bt + (size_t)rA0 * K + colA;

  float4 a0[2], a1[2];
  bf16x8 bgl[4];
  auto ldglb = [&](int k0) {
    a0[0] = *(const float4*)(pA0 + k0);
    a0[1] = *(const float4*)(pA0 + k0 + 4);
    a1[0] = *(const float4*)(pA1 + k0);
    a1[1] = *(const float4*)(pA1 + k0 + 4);
#pragma unroll
    for (int q = 0; q < 4; q++)
      bgl[q] = *(const bf16x8*)(pB + (size_t)(q * 64) * K + k0);
  };

  f32x4 zero = {0.f, 0.f, 0.f, 0.f};
  f32x4 acc[4][8];
#pragma unroll
  for (int i = 0; i < 4; i++)
#pragma unroll
    for (int j = 0; j < 8; j++) acc[i][j] = zero;

  ldglb(0);
  for (int k0 = 0; k0 < K; k0 += 32) {
    // stage prefetched regs -> LDS (cvt A on the way)
    bf16x8 pk0, pk1;
    pk0[0] = f2bf(a0[0].x); pk0[1] = f2bf(a0[0].y); pk0[2] = f2bf(a0[0].z); pk0[3] = f2bf(a0[0].w);
    pk0[4] = f2bf(a0[1].x); pk0[5] = f2bf(a0[1].y); pk0[6] = f2bf(a0[1].z); pk0[7] = f2bf(a0[1].w);
    pk1[0] = f2bf(a1[0].x); pk1[1] = f2bf(a1[0].y); pk1[2] = f2bf(a1[0].z); pk1[3] = f2bf(a1[0].w);
    pk1[4] = f2bf(a1[1].x); pk1[5] = f2bf(a1[1].y); pk1[6] = f2bf(a1[1].z); pk1[7] = f2bf(a1[1].w);
    *(bf16x8*)&As[tid * 8] = pk0;
    *(bf16x8*)&As[(tid + 256) * 8] = pk1;
#pragma unroll
    for (int q = 0; q < 4; q++) *(bf16x8*)&Bs[(tid + q * 256) * 8] = bgl[q];
    __syncthreads();

    if (k0 + 32 < K) ldglb(k0 + 32);  // next tile's globals in flight across MFMA

    bf16x8 af[4], bfr[8];
#pragma unroll
    for (int i = 0; i < 4; i++)
      af[i] = *(const bf16x8*)&As[(wm + i * 16 + lrow) * 32 + quad * 8];
#pragma unroll
    for (int j = 0; j < 8; j++)
      bfr[j] = *(const bf16x8*)&Bs[(wn + j * 16 + lrow) * 32 + quad * 8];
#pragma unroll
    for (int i = 0; i < 4; i++)
#pragma unroll
      for (int j = 0; j < 8; j++)
        acc[i][j] = __builtin_amdgcn_mfma_f32_16x16x32_bf16(af[i], bfr[j],
                                                            acc[i][j], 0, 0, 0);
    __syncthreads();
  }

#pragma unroll
  for (int i = 0; i < 4; i++) {
#pragma unroll
    for (int r = 0; r < 4; r++) {
      int grow = tile_m + wm + i * 16 + quad * 4 + r;
      if (grow < M) {
#pragma unroll
        for (int j = 0; j < 8; j++) {
          int gcol = wn + j * 16 + lrow;
          C[(size_t)grow * HID + gcol] = f2bf(acc[i][j][r]);
        }
      }
    }
  }
}

// ---------------- async MFMA GEMM (m97 structure), bf16 A ----------------
__device__ inline void glds16(const short* g, short* l) {
  __builtin_amdgcn_global_load_lds((const __attribute__((address_space(1))) void*)g,
                                   (__attribute__((address_space(3))) void*)l, 16, 0, 0);
}

__global__ __launch_bounds__(256) void k_gemm_a(const short* __restrict__ A,
                                                const short* __restrict__ Bt,
                                                short* __restrict__ C,
                                                int M, int N, int K) {
  __shared__ __align__(16) short As[128 * 32];
  __shared__ __align__(16) short Bs[128 * 32];
  const int tid = threadIdx.x;
  const int tile_m = blockIdx.x * 128;
  const int tile_n = blockIdx.y * 128;
  const int wave = tid >> 6;
  const int lane = tid & 63;
  const int wm = (wave & 1) * 64;
  const int wn = (wave >> 1) * 64;
  const int lrow = lane & 15;
  const int quad = lane >> 4;

  const int c = tid, c2 = tid + 256;
  const int rowA = c >> 2, colA = (c & 3) * 8;
  const int rowA2 = c2 >> 2, colA2 = (c2 & 3) * 8;
  int grA = tile_m + rowA;  if (grA >= M) grA = M - 1;
  int grA2 = tile_m + rowA2; if (grA2 >= M) grA2 = M - 1;
  const short* pA = A + (size_t)grA * K + colA;
  const short* pA2 = A + (size_t)grA2 * K + colA2;
  const short* pB = Bt + (size_t)(tile_n + rowA) * K + colA;
  const short* pB2 = Bt + (size_t)(tile_n + rowA2) * K + colA2;

  f32x4 zero = {0.f, 0.f, 0.f, 0.f};
  f32x4 acc[4][4];
#pragma unroll
  for (int i = 0; i < 4; i++)
#pragma unroll
    for (int j = 0; j < 4; j++) acc[i][j] = zero;

  for (int k0 = 0; k0 < K; k0 += 32) {
    glds16(pA + k0, &As[c * 8]);
    glds16(pA2 + k0, &As[c2 * 8]);
    glds16(pB + k0, &Bs[c * 8]);
    glds16(pB2 + k0, &Bs[c2 * 8]);
    __builtin_amdgcn_s_waitcnt(0xcf70);  // vmcnt(0)
    __syncthreads();

    bf16x8 af[4], bfr[4];
#pragma unroll
    for (int i = 0; i < 4; i++)
      af[i] = *(const bf16x8*)&As[(wm + i * 16 + lrow) * 32 + quad * 8];
#pragma unroll
    for (int j = 0; j < 4; j++)
      bfr[j] = *(const bf16x8*)&Bs[(wn + j * 16 + lrow) * 32 + quad * 8];
#pragma unroll
    for (int i = 0; i < 4; i++)
#pragma unroll
      for (int j = 0; j < 4; j++)
        acc[i][j] = __builtin_amdgcn_mfma_f32_16x16x32_bf16(af[i], bfr[j],
                                                            acc[i][j], 0, 0, 0);
    __syncthreads();
  }

#pragma unroll
  for (int i = 0; i < 4; i++) {
#pragma unroll
    for (int r = 0; r < 4; r++) {
      int grow = tile_m + wm + i * 16 + quad * 4 + r;
      if (grow < M) {
#pragma unroll
        for (int j = 0; j < 4; j++) {
          int gcol = tile_n + wn + j * 16 + lrow;
          C[(size_t)grow * N + gcol] = f2bf(acc[i][j][r]);
        }
      }
    }
  }
}

// ---------------- CSR aggregation: wave per node, unroll-4 edge loop ------
template <int F, bool RELU, typename OT>
__global__ __launch_bounds__(256) void k_agg2(const short* __restrict__ H,
                                              const int* __restrict__ rowp,
                                              const int* __restrict__ ssrc,
                                              const float* __restrict__ dinv,
                                              const float* __restrict__ bias,
                                              OT* __restrict__ out, int n) {
  constexpr int EPL = F / 64;  // 4 (F=256) or 2 (F=128)
  const int lane = threadIdx.x & 63;
  const int i = blockIdx.x * 4 + (threadIdx.x >> 6);
  if (i >= n) return;
  const int fo = lane * EPL;
  const float di = dinv[i];
  float acc[EPL];
  {
    const short* r = H + (size_t)i * F + fo;
    if constexpr (EPL == 4) {
      uint2 u = *(const uint2*)r;
      acc[0] = di * bf2f(u.x & 0xffffu); acc[1] = di * bf2f(u.x >> 16);
      acc[2] = di * bf2f(u.y & 0xffffu); acc[3] = di * bf2f(u.y >> 16);
    } else {
      uint32_t u = *(const uint32_t*)r;
      acc[0] = di * bf2f(u & 0xffffu); acc[1] = di * bf2f(u >> 16);
    }
  }
  int p = rowp[i];
  const int e1 = rowp[i + 1];
  for (; p + 4 <= e1; p += 4) {
    int s0 = __builtin_amdgcn_readfirstlane(ssrc[p]);
    int s1 = __builtin_amdgcn_readfirstlane(ssrc[p + 1]);
    int s2 = __builtin_amdgcn_readfirstlane(ssrc[p + 2]);
    int s3 = __builtin_amdgcn_readfirstlane(ssrc[p + 3]);
    float d0 = dinv[s0], d1 = dinv[s1], d2 = dinv[s2], d3 = dinv[s3];
    if constexpr (EPL == 4) {
      uint2 u0 = *(const uint2*)(H + (size_t)s0 * F + fo);
      uint2 u1 = *(const uint2*)(H + (size_t)s1 * F + fo);
      uint2 u2 = *(const uint2*)(H + (size_t)s2 * F + fo);
      uint2 u3 = *(const uint2*)(H + (size_t)s3 * F + fo);
      acc[0] += d0 * bf2f(u0.x & 0xffffu); acc[1] += d0 * bf2f(u0.x >> 16);
      acc[2] += d0 * bf2f(u0.y & 0xffffu); acc[3] += d0 * bf2f(u0.y >> 16);
      acc[0] += d1 * bf2f(u1.x & 0xffffu); acc[1] += d1 * bf2f(u1.x >> 16);
      acc[2] += d1 * bf2f(u1.y & 0xffffu); acc[3] += d1 * bf2f(u1.y >> 16);
      acc[0] += d2 * bf2f(u2.x & 0xffffu); acc[1] += d2 * bf2f(u2.x >> 16);
      acc[2] += d2 * bf2f(u2.y & 0xffffu); acc[3] += d2 * bf2f(u2.y >> 16);
      acc[0] += d3 * bf2f(u3.x & 0xffffu); acc[1] += d3 * bf2f(u3.x >> 16);
      acc[2] += d3 * bf2f(u3.y & 0xffffu); acc[3] += d3 * bf2f(u3.y >> 16);
    } else {
      uint32_t u0 = *(const uint32_t*)(H + (size_t)s0 * F + fo);
      uint32_t u1 = *(const uint32_t*)(H + (size_t)s1 * F + fo);
      uint32_t u2 = *(const uint32_t*)(H + (size_t)s2 * F + fo);
      uint32_t u3 = *(const uint32_t*)(H + (size_t)s3 * F + fo);
      acc[0] += d0 * bf2f(u0 & 0xffffu); acc[1] += d0 * bf2f(u0 >> 16);
      acc[0] += d1 * bf2f(u1 & 0xffffu); acc[1] += d1 * bf2f(u1 >> 16);
      acc[0] += d2 * bf2f(u2 & 0xffffu); acc[1] += d2 * bf2f(u2 >> 16);
      acc[0] += d3 * bf2f(u3 & 0xffffu); acc[1] += d3 * bf2f(u3 >> 16);
    }
  }
  for (; p < e1; ++p) {
    int s = __builtin_amdgcn_readfirstlane(ssrc[p]);
    float ds = dinv[s];
    if constexpr (EPL == 4) {
      uint2 u = *(const uint2*)(H + (size_t)s * F + fo);
      acc[0] += ds * bf2f(u.x & 0xffffu); acc[1] += ds * bf2f(u.x >> 16);
      acc[2] += ds * bf2f(u.y & 0xffffu); acc[3] += ds * bf2f(u.y >> 16);
    } else {
      uint32_t u = *(const uint32_t*)(H + (size_t)s * F + fo);
      acc[0] += ds * bf2f(u & 0xffffu); acc[1] += ds * bf2f(u >> 16);
    }
  }

  float o[EPL];
#pragma unroll
  for (int e2 = 0; e2 < EPL; ++e2) {
    o[e2] = di * acc[e2] + bias[fo + e2];
    if (RELU) o[e2] = fmaxf(o[e2], 0.f);
  }
  if constexpr (sizeof(OT) == 2) {
    if constexpr (EPL == 4) {
      uint2 pk;
      pk.x = (uint32_t)(uint16_t)f2bf(o[0]) | ((uint32_t)(uint16_t)f2bf(o[1]) << 16);
      pk.y = (uint32_t)(uint16_t)f2bf(o[2]) | ((uint32_t)(uint16_t)f2bf(o[3]) << 16);
      *(uint2*)((short*)out + (size_t)i * F + fo) = pk;
    } else {
      uint32_t pk = (uint32_t)(uint16_t)f2bf(o[0]) | ((uint32_t)(uint16_t)f2bf(o[1]) << 16);
      *(uint32_t*)((short*)out + (size_t)i * F + fo) = pk;
    }
  } else {
    if constexpr (EPL == 4) {
      *(float4*)((float*)out + (size_t)i * F + fo) = make_float4(o[0], o[1], o[2], o[3]);
    } else {
      *(float2*)((float*)out + (size_t)i * F + fo) = make_float2(o[0], o[1]);
    }
  }
}

// ---------------- launch ----------------
extern "C" void kernel_launch(void* const* d_in, const int* in_sizes, int n_in,
                              void* d_out, int out_size, void* d_ws, size_t ws_size,
                              hipStream_t stream) {
  const float* x = (const float*)d_in[0];
  const int* ei = (const int*)d_in[1];
  const float* W1 = (const float*)d_in[2];
  const float* b1 = (const float*)d_in[3];
  const float* W2 = (const float*)d_in[4];
  const float* b2 = (const float*)d_in[5];
  float* out = (float*)d_out;

  const int n = in_sizes[0] / IN_F;   // 50000
  const int e = in_sizes[1] / 2;      // 800000
  const int* e_src = ei;
  const int* e_dst = ei + e;
  const int nb = (n + SCAN_B - 1) / SCAN_B;

  uint8_t* ws = (uint8_t*)d_ws;
  size_t off = 0;
  auto carve = [&](size_t bytes) {
    uint8_t* p = ws + off;
    off = (off + bytes + 255) & ~(size_t)255;
    return p;
  };
  short* h1 = (short*)carve((size_t)n * HID * 2);
  short* h2 = (short*)carve((size_t)n * HID * 2);
  short* t2 = (short*)carve((size_t)n * OUTF * 2);
  short* w1t = (short*)carve((size_t)HID * IN_F * 2);
  short* w2t = (short*)carve((size_t)OUTF * HID * 2);
  int* cnt = (int*)carve((size_t)n * 4);
  int* rowp = (int*)carve((size_t)(n + 1) * 4);
  int* cursor = (int*)carve((size_t)n * 4);
  float* dinv = (float*)carve((size_t)n * 4);
  int* ssrc = (int*)carve((size_t)e * 4);
  int* bsum = (int*)carve((size_t)nb * 4);
  int* boff = (int*)carve((size_t)nb * 4);
  (void)n_in; (void)out_size; (void)ws_size;

  // CSR build
  k_zero<<<(n + 255) / 256, 256, 0, stream>>>(cnt, n);
  k_hist<<<(e + 255) / 256, 256, 0, stream>>>(e_dst, cnt, e);
  k_bsum<<<nb, SCAN_B, 0, stream>>>(cnt, bsum, n);
  k_bscan<<<1, 64, 0, stream>>>(bsum, boff, nb);
  k_scan2<<<nb, SCAN_B, 0, stream>>>(cnt, boff, rowp, cursor, dinv, n);
  k_fill<<<(e + 255) / 256, 256, 0, stream>>>(e_src, e_dst, cursor, ssrc, e);

  // weights
  k_tw<<<(IN_F * HID + 255) / 256, 256, 0, stream>>>(W1, w1t, IN_F, HID);
  k_tw<<<(HID * OUTF + 255) / 256, 256, 0, stream>>>(W2, w2t, HID, OUTF);

  // layer 1: h1 = x @ W1 (direct f32 A, read once); h2 = relu(agg(h1)+b1)
  k_gemm1<<<(n + 127) / 128, 256, 0, stream>>>(x, w1t, h1, n, IN_F);
  k_agg2<HID, true, short><<<(n + 3) / 4, 256, 0, stream>>>(h1, rowp, ssrc, dinv, b1, h2, n);

  // layer 2: t2 = h2 @ W2 ; out = agg(t2) + b2
  {
    dim3 grid((n + 127) / 128, OUTF / 128);
    k_gemm_a<<<grid, 256, 0, stream>>>(h2, w2t, t2, n, OUTF, HID);
  }
  k_agg2<OUTF, false, float><<<(n + 3) / 4, 256, 0, stream>>>(t2, rowp, ssrc, dinv, b2, out, n);
}